// Round 6
// baseline (697.733 us; speedup 1.0000x reference)
//
#include <hip/hip_runtime.h>
#include <hip/hip_bf16.h>
#include <cstdint>

typedef __hip_bfloat16 bf16;
typedef __attribute__((ext_vector_type(8))) short short8;
typedef __attribute__((ext_vector_type(4))) float f32x4;

// ---------------------------------------------------------------------------
// async global->LDS, 16B/lane (wave-uniform LDS base + lane*16 implicit)
// ---------------------------------------------------------------------------
__device__ __forceinline__ void gload16(const bf16* g, bf16* l) {
    __builtin_amdgcn_global_load_lds(
        (__attribute__((address_space(1))) void*)g,
        (__attribute__((address_space(3))) void*)l, 16, 0, 0);
}
#define VMC(n) asm volatile("s_waitcnt vmcnt(" #n ")" ::: "memory")
#define LGKM0 asm volatile("s_waitcnt lgkmcnt(0)" ::: "memory")
__device__ __forceinline__ void bar() {
    asm volatile("" ::: "memory");
    __builtin_amdgcn_s_barrier();
    asm volatile("" ::: "memory");
}

// ---------------------------------------------------------------------------
// stage one half-tile [128 rows x 64 cols bf16] into a linear LDS region.
// Source pre-swizzled: LDS(r, slot) = G(r, slot ^ (r&7)) [16B slots] so the
// swizzled ds_reads are conflict-free while global_load_lds writes linearly.
// ---------------------------------------------------------------------------
__device__ __forceinline__ void stage_half(const bf16* __restrict__ G, int ld,
                                           int row0, int k0, bf16* lregion,
                                           int w, int lrow, int lslot)
{
    const bf16* s0 = G + (long long)(row0 + w * 8 + lrow) * ld + (k0 + lslot * 8);
    gload16(s0, lregion + (w * 64) * 8);
    gload16(s0 + (long long)64 * ld, lregion + (512 + w * 64) * 8);
}

// compiler-scheduled fragment loads (proven round-2 form; asm ladder regressed)
#define LOAD_A(mh) do { _Pragma("unroll") for (int i_ = 0; i_ < 4; ++i_) { \
    _Pragma("unroll") for (int ks_ = 0; ks_ < 2; ++ks_) \
      aF[i_][ks_] = *(const short8*)(pa + ((mh) * 64 + i_ * 16 + l15) * 64 \
                                        + (((ks_ * 4 + lq) ^ l7) * 8)); } } while (0)
#define LOAD_B(nh, dst) do { _Pragma("unroll") for (int j_ = 0; j_ < 2; ++j_) { \
    _Pragma("unroll") for (int ks_ = 0; ks_ < 2; ++ks_) \
      dst[j_][ks_] = *(const short8*)(pb + (bhr + (nh) * 32 + j_ * 16 + l15) * 64 \
                                         + (((ks_ * 4 + lq) ^ l7) * 8)); } } while (0)
#define DO_Q(mh, nh, BF) do { \
    __builtin_amdgcn_s_setprio(1); \
    _Pragma("unroll") for (int i_ = 0; i_ < 4; ++i_) \
      _Pragma("unroll") for (int j_ = 0; j_ < 2; ++j_) \
        _Pragma("unroll") for (int ks_ = 0; ks_ < 2; ++ks_) \
          acc[mh][nh][i_][j_] = __builtin_amdgcn_mfma_f32_16x16x32_bf16( \
              aF[i_][ks_], BF[j_][ks_], acc[mh][nh][i_][j_], 0, 0, 0); \
    __builtin_amdgcn_s_setprio(0); \
} while (0)

// ---------------------------------------------------------------------------
// 256x256 8-phase bf16 GEMM, C = A*B^T (+bias)(+leakyrelu).
// BIASMODE: 0 none; 1 per-column bias[gc]; 2 row-dep table bias[(row&511)*W+gc]
//           with W passed in segStride.
// ROUTE: output col gc -> matrix gc/1152, local col gc%1152 (fused q|k|v).
// Writes guarded by gc < nwrite.
// ---------------------------------------------------------------------------
template<int OUT_BF16, int ACT, int BIASMODE, int ROUTE>
__global__ __launch_bounds__(512, 2)
void gemm256(const bf16* __restrict__ Abase, const bf16* __restrict__ Bbase,
             void* __restrict__ Cbase, const float* __restrict__ bias,
             int K, int lda, int ldb, int ldc, int nwrite,
             long long sA, long long sB, long long sC, long long segStride)
{
    __shared__ bf16 lds[2][2][2][8192];   // [buf][op][half][128*64], 128 KiB

    // XCD-bijective chunk swizzle (T1/m204) over 3D linear block id
    const int gx = gridDim.x, gy = gridDim.y;
    const int nwg = gx * gy * gridDim.z;
    const int lin = blockIdx.x + gx * (blockIdx.y + gy * blockIdx.z);
    const int qch = nwg >> 3, rch = nwg & 7;
    const int xcd = lin & 7, pos = lin >> 3;
    const int nl = (xcd < rch ? xcd * (qch + 1)
                              : rch * (qch + 1) + (xcd - rch) * qch) + pos;
    const int bz = nl / (gx * gy);
    const int rem = nl - bz * (gx * gy);
    const int by = rem / gx;
    const int bx = rem - by * gx;

    const int tid = threadIdx.x;
    const int wid = tid >> 6, lane = tid & 63;
    const int wm = wid >> 2, wn = wid & 3;          // 2 x 4 waves
    const int l15 = lane & 15, l7 = lane & 7, lq = lane >> 4;
    const int lrow = lane >> 3, lslot = l7 ^ lrow;  // staging per-lane geom
    const int bhr = (wn & 1) * 64;                  // B row base within half

    const bf16* A = Abase + (long long)bz * sA;
    const bf16* B = Bbase + (long long)bz * sB;
    const int brow = by * 256, bcol = bx * 256;

    f32x4 acc[2][2][4][2] = {};
    short8 aF[4][2], bF0[2][2], bF1[2][2];

    const int nt = K >> 6;

    // ---- prologue: t0.B, t0.A -> buf0 ; t1.B -> buf1 ----
    stage_half(B, ldb, bcol,       0,  &lds[0][1][0][0], wid, lrow, lslot);
    stage_half(B, ldb, bcol + 128, 0,  &lds[0][1][1][0], wid, lrow, lslot);
    stage_half(A, lda, brow,       0,  &lds[0][0][0][0], wid, lrow, lslot);
    stage_half(A, lda, brow + 128, 0,  &lds[0][0][1][0], wid, lrow, lslot);
    stage_half(B, ldb, bcol,       64, &lds[1][1][0][0], wid, lrow, lslot);
    stage_half(B, ldb, bcol + 128, 64, &lds[1][1][1][0], wid, lrow, lslot);
    VMC(4);
    bar();

    for (int t = 0; t < nt; ++t) {
        const int b = t & 1;
        const bf16* pa = &lds[b][0][wm][0];
        const bf16* pb = &lds[b][1][wn >> 1][0];
        bf16* oA = &lds[b ^ 1][0][0][0];   // next tile's A -> other buffer
        bf16* cB = &lds[b][1][0][0];       // tile t+2's B -> current buffer
        const int t1 = (t + 1 == nt) ? 0 : t + 1;
        const int t2 = (t + 2 >= nt) ? t + 2 - nt : t + 2;
        const int k1 = t1 << 6, k2 = t2 << 6;

        // ---- phase 1: Q(0,0); stage (t+1).A0 ----
        LOAD_A(0); LOAD_B(0, bF0);
        stage_half(A, lda, brow, k1, oA, wid, lrow, lslot);
        bar();
        DO_Q(0, 0, bF0);
        LGKM0; bar();

        // ---- phase 2: Q(0,1); stage (t+1).A1 ----
        LOAD_B(1, bF1);
        stage_half(A, lda, brow + 128, k1, oA + 8192, wid, lrow, lslot);
        bar();
        DO_Q(0, 1, bF1);
        LGKM0; bar();

        // ---- phase 3: Q(1,1); stage (t+2).B0 (B0 dead after phase 2) ----
        LOAD_A(1);
        stage_half(B, ldb, bcol, k2, cB, wid, lrow, lslot);
        bar();
        DO_Q(1, 1, bF1);
        LGKM0; bar();

        // ---- phase 4: Q(1,0); stage (t+2).B1; counted vmcnt ----
        stage_half(B, ldb, bcol + 128, k2, cB + 8192, wid, lrow, lslot);
        bar();
        DO_Q(1, 0, bF0);
        VMC(4);
        bar();
    }
    VMC(0);   // drain wrapped stray stages

    // ---- epilogue: C/D layout col = lane&15, row = (lane>>4)*4 + rr ----
    const long long cofs0 = (long long)bz * sC;
    #pragma unroll
    for (int mh = 0; mh < 2; ++mh)
      #pragma unroll
      for (int nh = 0; nh < 2; ++nh)
        #pragma unroll
        for (int i = 0; i < 4; ++i)
          #pragma unroll
          for (int j = 0; j < 2; ++j) {
              const int gc = bcol + wn * 64 + nh * 32 + j * 16 + l15;
              int lc = gc;
              long long cofs = cofs0;
              if (ROUTE) {
                  const unsigned seg = (unsigned)gc / 1152u;
                  lc = gc - (int)(seg * 1152u);
                  cofs += (long long)seg * segStride;
              }
              const bool wr = gc < nwrite;
              const float bvv = (BIASMODE == 1 && wr) ? bias[gc] : 0.0f;
              const int row0 = brow + wm * 128 + mh * 64 + i * 16 + lq * 4;
              if (wr) {
                  #pragma unroll
                  for (int rr = 0; rr < 4; ++rr) {
                      float vv = acc[mh][nh][i][j][rr];
                      if (BIASMODE == 2)
                          vv += bias[((row0 + rr) & 511) * (int)segStride + gc];
                      else
                          vv += bvv;
                      if (ACT) vv = vv > 0.0f ? vv : 0.2f * vv;
                      const long long cidx = cofs + (long long)(row0 + rr) * ldc + lc;
                      if (OUT_BF16) ((bf16*)Cbase)[cidx] = (bf16)vv;
                      else          ((float*)Cbase)[cidx] = vv;
                  }
              }
          }
}

// ---------------------------------------------------------------------------
// pure cast: x f32 [32768*1024] -> bf16
// ---------------------------------------------------------------------------
__global__ void cast_kernel(const float* __restrict__ x, bf16* __restrict__ xb)
{
    const long long i = ((long long)blockIdx.x * 256 + threadIdx.x) * 8;
    float4 a = *(const float4*)&x[i];
    float4 b = *(const float4*)&x[i + 4];
    bf16 t[8] = { (bf16)a.x, (bf16)a.y, (bf16)a.z, (bf16)a.w,
                  (bf16)b.x, (bf16)b.y, (bf16)b.z, (bf16)b.w };
    *(ushort4*)&xb[i]     = *(ushort4*)&t[0];
    *(ushort4*)&xb[i + 4] = *(ushort4*)&t[4];
}

// ---------------------------------------------------------------------------
// E[s][n] = b1[n] + sum_k emb[s][k] * w1[1024+k][n]  (f32, n<1056; else 0)
// one block per s; w1 slice is L2-resident after first blocks.
// ---------------------------------------------------------------------------
__global__ void embE_kernel(const float* __restrict__ emb, const float* __restrict__ w1,
                            const float* __restrict__ b1, float* __restrict__ E)
{
    const int s = blockIdx.x;
    __shared__ float es[32];
    if (threadIdx.x < 32) es[threadIdx.x] = emb[s * 32 + threadIdx.x];
    __syncthreads();
    for (int n = threadIdx.x; n < 1280; n += 256) {
        float acc = 0.0f;
        if (n < 1056) {
            acc = b1[n];
            #pragma unroll
            for (int k = 0; k < 32; ++k)
                acc += es[k] * w1[(long long)(1024 + k) * 1056 + n];
        }
        E[(long long)s * 1280 + n] = acc;
    }
}

// ---------------------------------------------------------------------------
// batched weight transpose-cast into bf16 [NP][KP] (zero-padded).
// z: 0 w1 rows0..1023 -> w1xT[1280][1024]; 1..3 wq/wk/wv -> wqkvT segments
// (1152-row pitch, z=3 NP=1280 zeroes the tail to 3584); 4 w2 -> w2T.
// ---------------------------------------------------------------------------
__global__ void wtrans5_kernel(const float* __restrict__ w1, const float* __restrict__ wq,
                               const float* __restrict__ wk, const float* __restrict__ wv,
                               const float* __restrict__ w2,
                               bf16* __restrict__ w1xT, bf16* __restrict__ wqkvT,
                               bf16* __restrict__ w2T)
{
    const int z = blockIdx.z;
    const float* src; bf16* dst; int KIN, KP, NIN, NP, srcld;
    switch (z) {
        case 0: src = w1; dst = w1xT;                  KIN = 1024; KP = 1024; NIN = 1056; NP = 1280; srcld = 1056; break;
        case 1: src = wq; dst = wqkvT;                 KIN = 1056; KP = 1088; NIN = 1056; NP = 1152; srcld = 1056; break;
        case 2: src = wk; dst = wqkvT + 1152LL * 1088; KIN = 1056; KP = 1088; NIN = 1056; NP = 1152; srcld = 1056; break;
        case 3: src = wv; dst = wqkvT + 2304LL * 1088; KIN = 1056; KP = 1088; NIN = 1056; NP = 1280; srcld = 1056; break;
        default: src = w2; dst = w2T;                  KIN = 1056; KP = 1088; NIN = 1024; NP = 1024; srcld = 1024; break;
    }
    const int k0 = blockIdx.x * 32, n0 = blockIdx.y * 32;
    if (k0 >= KP || n0 >= NP) return;
    __shared__ float t[32][33];
    const int tx = threadIdx.x, ty = threadIdx.y;
    const int kk = k0 + ty, nn = n0 + tx;
    t[ty][tx] = (kk < KIN && nn < NIN) ? src[(long long)kk * srcld + nn] : 0.0f;
    __syncthreads();
    const int ko = k0 + tx, no = n0 + ty;
    if (no < NP && ko < KP)
        dst[(long long)no * KP + ko] = (bf16)t[tx][ty];
}

// ---------------------------------------------------------------------------
// bias prep: bqkv[3456] (1152-seg), b2p[1024]
// ---------------------------------------------------------------------------
__global__ void biasprep_kernel(const float* __restrict__ bq, const float* __restrict__ bk,
                                const float* __restrict__ bv, const float* __restrict__ b2,
                                float* __restrict__ bqkv, float* __restrict__ b2p)
{
    const int i = blockIdx.x * 256 + threadIdx.x;
    if (i < 3456) {
        const int seg = i / 1152, c = i - seg * 1152;
        const float* src = seg == 0 ? bq : (seg == 1 ? bk : bv);
        bqkv[i] = (c < 1056) ? src[c] : 0.0f;
    } else if (i < 3456 + 1024) {
        b2p[i - 3456] = b2[i - 3456];
    }
}

// ---------------------------------------------------------------------------
// batched bf16 transpose: v [64][512][1152] -> vT [64][1280][512]
// (vT rows >= 1152 zero-filled)
// ---------------------------------------------------------------------------
__global__ void vtrans_kernel(const bf16* __restrict__ v, bf16* __restrict__ vt)
{
    __shared__ bf16 t[64][72];
    const long long b = blockIdx.z;
    const bf16* vb = v + b * (512LL * 1152);
    bf16* vtb = vt + b * (1280LL * 512);
    const int d0 = blockIdx.x * 64, s0 = blockIdx.y * 64;
    const int tx = threadIdx.x & 15, ty = threadIdx.x >> 4;   // 16x16
    const bool zz = d0 >= 1152;
    #pragma unroll
    for (int i = 0; i < 4; ++i) {
        const int row = ty + i * 16;
        ushort4 val = make_ushort4(0, 0, 0, 0);
        if (!zz)
            val = *(const ushort4*)&vb[(long long)(s0 + row) * 1152 + d0 + tx * 4];
        *(ushort4*)&t[row][tx * 4] = val;
    }
    __syncthreads();
    #pragma unroll
    for (int i = 0; i < 4; ++i) {
        const int d = ty + i * 16;
        ushort4 o;
        o.x = *(const ushort*)&t[tx * 4 + 0][d];
        o.y = *(const ushort*)&t[tx * 4 + 1][d];
        o.z = *(const ushort*)&t[tx * 4 + 2][d];
        o.w = *(const ushort*)&t[tx * 4 + 3][d];
        *(ushort4*)&vtb[(long long)(d0 + d) * 512 + s0 + tx * 4] = o;
    }
}

// ---------------------------------------------------------------------------
// row softmax: energy f32 [32768,512] -> attn bf16 [32768,512]; 1 wave/row
// ---------------------------------------------------------------------------
__global__ __launch_bounds__(256)
void softmax_kernel(const float* __restrict__ e, bf16* __restrict__ p)
{
    const int wid = threadIdx.x >> 6, lane = threadIdx.x & 63;
    const long long row = (long long)blockIdx.x * 4 + wid;
    const float* er = e + row * 512;
    float v[8];
    float mx = -3.0e38f;
    #pragma unroll
    for (int j = 0; j < 8; ++j) { v[j] = er[j * 64 + lane]; mx = fmaxf(mx, v[j]); }
    #pragma unroll
    for (int s = 32; s > 0; s >>= 1) mx = fmaxf(mx, __shfl_xor(mx, s));
    float sum = 0.0f;
    #pragma unroll
    for (int j = 0; j < 8; ++j) { v[j] = __expf(v[j] - mx); sum += v[j]; }
    #pragma unroll
    for (int s = 32; s > 0; s >>= 1) sum += __shfl_xor(sum, s);
    const float inv = 1.0f / sum;
    bf16* pr = p + row * 512;
    #pragma unroll
    for (int j = 0; j < 8; ++j) pr[j * 64 + lane] = (bf16)(v[j] * inv);
}

// ---------------------------------------------------------------------------
extern "C" void kernel_launch(void* const* d_in, const int* in_sizes, int n_in,
                              void* d_out, int out_size, void* d_ws, size_t ws_size,
                              hipStream_t stream)
{
    const float* x   = (const float*)d_in[0];
    const float* emb = (const float*)d_in[1];
    const float* w1  = (const float*)d_in[2];
    const float* b1  = (const float*)d_in[3];
    const float* wq  = (const float*)d_in[4];
    const float* bq  = (const float*)d_in[5];
    const float* wk  = (const float*)d_in[6];
    const float* bk  = (const float*)d_in[7];
    const float* wv  = (const float*)d_in[8];
    const float* bv  = (const float*)d_in[9];
    const float* w2  = (const float*)d_in[10];
    const float* b2  = (const float*)d_in[11];
    float* out = (float*)d_out;

    const long long Mrows = 32768;   // 64 * 512
    const int KR = 1088;             // downstream K (17*64 >= 1056)
    const int WQ = 1152;             // stored width of q/k/v

    char* ws = (char*)d_ws;
    size_t off = 0;
    auto alloc = [&](size_t bytes) -> char* {
        char* p = ws + off;
        off += (bytes + 255) & ~(size_t)255;
        return p;
    };
    char* R1    = alloc((size_t)Mrows * KR * 2);            // xb / energy / pv
    char* R2    = alloc((size_t)64 * 1280 * 512 * 2);       // h / vT
    bf16* qkv   = (bf16*)alloc((size_t)3 * Mrows * WQ * 2); // q | k | v
    bf16* w1xT  = (bf16*)alloc((size_t)1280 * 1024 * 2);
    bf16* wqkvT = (bf16*)alloc((size_t)3584 * KR * 2);
    bf16* w2T   = (bf16*)alloc((size_t)1024 * KR * 2);
    float* Etab = (float*)alloc((size_t)512 * 1280 * 4);
    float* bqkv = (float*)alloc((size_t)3456 * 4);
    float* b2p  = (float*)alloc((size_t)1024 * 4);

    bf16*  xb     = (bf16*)R1;                  // [32768][1024]
    float* energy = (float*)R1;                 // after l1 consumed xb
    bf16*  pv     = (bf16*)R1;                  // after softmax consumed energy
    bf16*  h      = (bf16*)R2;                  // [32768][1088]
    bf16*  vT     = (bf16*)R2;                  // after qkv consumed h
    bf16*  qb     = qkv;
    bf16*  kb     = qkv + Mrows * WQ;
    bf16*  vb     = qkv + 2 * Mrows * WQ;
    bf16*  attn   = kb;                         // k dead after energy

    cast_kernel<<<16384, 256, 0, stream>>>(x, xb);
    wtrans5_kernel<<<dim3(34, 40, 5), dim3(32, 32), 0, stream>>>(
        w1, wq, wk, wv, w2, w1xT, wqkvT, w2T);
    embE_kernel<<<512, 256, 0, stream>>>(emb, w1, b1, Etab);
    biasprep_kernel<<<18, 256, 0, stream>>>(bq, bk, bv, b2, bqkv, b2p);

    // h = leakyrelu(xb @ w1x^T + E[row&511])   M=32768 Ngrid=1280 K=1024
    gemm256<1, 1, 2, 0><<<dim3(5, 128, 1), 512, 0, stream>>>(
        xb, w1xT, h, Etab, 1024, 1024, 1024, KR, KR, 0, 0, 0, 1280);
    // q|k|v = h @ [wq|wk|wv]^T + bias          M=32768 Ngrid=3584 K=1088
    gemm256<1, 0, 1, 1><<<dim3(14, 128, 1), 512, 0, stream>>>(
        h, wqkvT, qkv, bqkv, KR, KR, KR, WQ, 3456, 0, 0, 0,
        (long long)Mrows * WQ);
    // vT (into dead h region)
    vtrans_kernel<<<dim3(20, 8, 64), 256, 0, stream>>>(vb, vT);
    // energy[b] = q_b @ k_b^T  (f32, into dead xb region)
    gemm256<0, 0, 0, 0><<<dim3(2, 2, 64), 512, 0, stream>>>(
        qb, kb, energy, nullptr, KR, WQ, WQ, 512, 512,
        512LL * WQ, 512LL * WQ, 512LL * 512, 0);
    // softmax rows -> bf16 (into dead k region)
    softmax_kernel<<<8192, 256, 0, stream>>>(energy, attn);
    // pv[b] = attn_b @ v_b (via vT; into dead energy region)
    gemm256<1, 0, 0, 0><<<dim3(5, 2, 64), 512, 0, stream>>>(
        attn, vT, pv, nullptr, 512, 512, 512, KR, KR,
        512LL * 512, 1280LL * 512, 512LL * KR, 0);
    // out = pv @ w2 + b2  (f32)
    gemm256<0, 0, 1, 0><<<dim3(4, 128, 1), 512, 0, stream>>>(
        pv, w2T, out, b2p, KR, KR, KR, 1024, 1024, 0, 0, 0, 0);
}

// Round 8
// 669.197 us; speedup vs baseline: 1.0426x; 1.0426x over previous
//
#include <hip/hip_runtime.h>
#include <hip/hip_bf16.h>
#include <cstdint>

typedef __hip_bfloat16 bf16;
typedef __attribute__((ext_vector_type(8))) short short8;
typedef __attribute__((ext_vector_type(4))) float f32x4;

// ---------------------------------------------------------------------------
// async global->LDS, 16B/lane (wave-uniform LDS base + lane*16 implicit)
// ---------------------------------------------------------------------------
__device__ __forceinline__ void gload16(const bf16* g, bf16* l) {
    __builtin_amdgcn_global_load_lds(
        (__attribute__((address_space(1))) void*)g,
        (__attribute__((address_space(3))) void*)l, 16, 0, 0);
}
#define VMC(n) asm volatile("s_waitcnt vmcnt(" #n ")" ::: "memory")
__device__ __forceinline__ void bar() {
    asm volatile("" ::: "memory");
    __builtin_amdgcn_s_barrier();
    asm volatile("" ::: "memory");
}

// ---------------------------------------------------------------------------
// stage one half-tile [128 rows x 64 cols bf16] into a linear LDS region.
// Source pre-swizzled: LDS(r, slot) = G(r, slot ^ (r&7)) [16B slots] so the
// swizzled ds_reads are conflict-free while global_load_lds writes linearly.
// ---------------------------------------------------------------------------
__device__ __forceinline__ void stage_half(const bf16* __restrict__ G, int ld,
                                           int row0, int k0, bf16* lregion,
                                           int w, int lrow, int lslot)
{
    const bf16* s0 = G + (long long)(row0 + w * 8 + lrow) * ld + (k0 + lslot * 8);
    gload16(s0, lregion + (w * 64) * 8);
    gload16(s0 + (long long)64 * ld, lregion + (512 + w * 64) * 8);
}

// NOTE (round-7 lesson): each wave reads ONLY its own region lds[b][0][wm];
// aFe = rows 0..63 of that region, aFo = rows 64..127. So ANY fragment read
// of tile t requires BOTH A stages of t drained -- no cross-tile prefetch.
#define LOAD_AI(dst, i_, mh, P) do { \
    _Pragma("unroll") for (int ks_ = 0; ks_ < 2; ++ks_) \
      dst[i_][ks_] = *(const short8*)((P) + ((mh) * 64 + (i_) * 16 + l15) * 64 \
                                         + (((ks_ * 4 + lq) ^ l7) * 8)); } while (0)
#define LOAD_B(nh, dst) do { _Pragma("unroll") for (int j_ = 0; j_ < 2; ++j_) { \
    _Pragma("unroll") for (int ks_ = 0; ks_ < 2; ++ks_) \
      dst[j_][ks_] = *(const short8*)(pb + (bhr + (nh) * 32 + j_ * 16 + l15) * 64 \
                                         + (((ks_ * 4 + lq) ^ l7) * 8)); } } while (0)
#define DO_Q(mh, nh, AF, BF) do { \
    __builtin_amdgcn_s_setprio(1); \
    _Pragma("unroll") for (int i_ = 0; i_ < 4; ++i_) \
      _Pragma("unroll") for (int j_ = 0; j_ < 2; ++j_) \
        _Pragma("unroll") for (int ks_ = 0; ks_ < 2; ++ks_) \
          acc[mh][nh][i_][j_] = __builtin_amdgcn_mfma_f32_16x16x32_bf16( \
              AF[i_][ks_], BF[j_][ks_], acc[mh][nh][i_][j_], 0, 0, 0); \
    __builtin_amdgcn_s_setprio(0); \
} while (0)

// ---------------------------------------------------------------------------
// 256x256 8-phase bf16 GEMM, C = A*B^T (+bias)(+leakyrelu).
// Schedule (single VMC(4)/tile at end of p4; FIFO ledger):
//   enter p1(t) with {B0(t+1),B1(t+1)} in flight (4 loads).
//   p1: read aFe+bF0+bF1 | stage A0(t+1) | bar | Q(0,0) | bar
//   p2: read aFo[0,1]    | stage A1(t+1) | bar | Q(0,1) | bar
//   p3: read aFo[2,3]    | stage B0(t+2) | bar | Q(1,1) | bar
//   p4:                    stage B1(t+2) | bar | Q(1,0) | VMC(4) | bar
//   VMC(4) drains B(t+1)+A(t+1) (8 oldest), leaves B(t+2) pair = 4.
// ROUTE: output col gc -> matrix gc/1152, local col gc%1152 (fused q|k|v).
// ---------------------------------------------------------------------------
template<int OUT_BF16, int ACT, int HAS_BIAS, int ROUTE>
__global__ __launch_bounds__(512, 2)
void gemm256(const bf16* __restrict__ Abase, const bf16* __restrict__ Bbase,
             void* __restrict__ Cbase, const float* __restrict__ bias,
             int K, int lda, int ldb, int ldc, int nwrite,
             long long sA, long long sB, long long sC, long long segStride)
{
    __shared__ bf16 lds[2][2][2][8192];   // [buf][op][half][128*64], 128 KiB

    // XCD-bijective chunk swizzle (T1/m204) over 3D linear block id
    const int gx = gridDim.x, gy = gridDim.y;
    const int nwg = gx * gy * gridDim.z;
    const int lin = blockIdx.x + gx * (blockIdx.y + gy * blockIdx.z);
    const int qch = nwg >> 3, rch = nwg & 7;
    const int xcd = lin & 7, pos = lin >> 3;
    const int nl = (xcd < rch ? xcd * (qch + 1)
                              : rch * (qch + 1) + (xcd - rch) * qch) + pos;
    const int bz = nl / (gx * gy);
    const int rem = nl - bz * (gx * gy);
    const int by = rem / gx;
    const int bx = rem - by * gx;

    const int tid = threadIdx.x;
    const int wid = tid >> 6, lane = tid & 63;
    const int wm = wid >> 2, wn = wid & 3;          // 2 x 4 waves
    const int l15 = lane & 15, l7 = lane & 7, lq = lane >> 4;
    const int lrow = lane >> 3, lslot = l7 ^ lrow;  // staging per-lane geom
    const int bhr = (wn & 1) * 64;                  // B row base within half

    const bf16* A = Abase + (long long)bz * sA;
    const bf16* B = Bbase + (long long)bz * sB;
    const int brow = by * 256, bcol = bx * 256;

    f32x4 acc[2][2][4][2] = {};
    short8 aFe[4][2], aFo[4][2], bF0[2][2], bF1[2][2];

    const int nt = K >> 6;

    // ---- prologue: t0.B, t0.A -> buf0 ; t1.B -> buf1 ----
    stage_half(B, ldb, bcol,       0,  &lds[0][1][0][0], wid, lrow, lslot);
    stage_half(B, ldb, bcol + 128, 0,  &lds[0][1][1][0], wid, lrow, lslot);
    stage_half(A, lda, brow,       0,  &lds[0][0][0][0], wid, lrow, lslot);
    stage_half(A, lda, brow + 128, 0,  &lds[0][0][1][0], wid, lrow, lslot);
    stage_half(B, ldb, bcol,       64, &lds[1][1][0][0], wid, lrow, lslot);
    stage_half(B, ldb, bcol + 128, 64, &lds[1][1][1][0], wid, lrow, lslot);
    VMC(4);   // drain B(0)+A(0); leaves B0(1),B1(1) = 4 (steady-state entry)
    bar();

    for (int t = 0; t < nt; ++t) {
        const int b = t & 1;
        const bf16* pa = &lds[b][0][wm][0];
        const bf16* pb = &lds[b][1][wn >> 1][0];
        bf16* oA = &lds[b ^ 1][0][0][0];   // next tile's A -> other buffer
        bf16* cB = &lds[b][1][0][0];       // tile t+2's B -> current buffer
        const int t1 = (t + 1 == nt) ? 0 : t + 1;
        const int t2 = (t + 2 >= nt) ? t + 2 - nt : t + 2;
        const int k1 = t1 << 6, k2 = t2 << 6;

        // ---- p1: read aFe + both B halves; stage A0(t+1); Q(0,0) ----
        LOAD_B(0, bF0);
        LOAD_AI(aFe, 0, 0, pa); LOAD_AI(aFe, 1, 0, pa);
        LOAD_AI(aFe, 2, 0, pa); LOAD_AI(aFe, 3, 0, pa);
        LOAD_B(1, bF1);
        stage_half(A, lda, brow, k1, oA, wid, lrow, lslot);
        bar();
        DO_Q(0, 0, aFe, bF0);
        bar();

        // ---- p2: read aFo[0,1]; stage A1(t+1); Q(0,1) (no new deps) ----
        LOAD_AI(aFo, 0, 1, pa); LOAD_AI(aFo, 1, 1, pa);
        stage_half(A, lda, brow + 128, k1, oA + 8192, wid, lrow, lslot);
        bar();
        DO_Q(0, 1, aFe, bF1);
        bar();

        // ---- p3: read aFo[2,3]; stage B0(t+2); Q(1,1) ----
        LOAD_AI(aFo, 2, 1, pa); LOAD_AI(aFo, 3, 1, pa);
        stage_half(B, ldb, bcol, k2, cB, wid, lrow, lslot);
        bar();
        DO_Q(1, 1, aFo, bF1);
        bar();

        // ---- p4: stage B1(t+2); Q(1,0) pure-MFMA; tile-boundary drain ----
        stage_half(B, ldb, bcol + 128, k2, cB + 8192, wid, lrow, lslot);
        bar();
        DO_Q(1, 0, aFo, bF0);
        VMC(4);   // drain B(t+1)+A(t+1); B(t+2) pair stays in flight
        bar();
    }
    VMC(0);   // drain wrapped stray stages

    // ---- epilogue: C/D layout col = lane&15, row = (lane>>4)*4 + rr ----
    const long long cofs0 = (long long)bz * sC;
    #pragma unroll
    for (int mh = 0; mh < 2; ++mh)
      #pragma unroll
      for (int nh = 0; nh < 2; ++nh)
        #pragma unroll
        for (int i = 0; i < 4; ++i)
          #pragma unroll
          for (int j = 0; j < 2; ++j) {
              const int gc = bcol + wn * 64 + nh * 32 + j * 16 + l15;
              int lc = gc;
              long long cofs = cofs0;
              if (ROUTE) {
                  const unsigned seg = (unsigned)gc / 1152u;
                  lc = gc - (int)(seg * 1152u);
                  cofs += (long long)seg * segStride;
              }
              const bool wr = gc < nwrite;
              const float bvv = (HAS_BIAS && wr) ? bias[gc] : 0.0f;
              const int row0 = brow + wm * 128 + mh * 64 + i * 16 + lq * 4;
              if (wr) {
                  #pragma unroll
                  for (int rr = 0; rr < 4; ++rr) {
                      float vv = acc[mh][nh][i][j][rr] + bvv;
                      if (ACT) vv = vv > 0.0f ? vv : 0.2f * vv;
                      const long long cidx = cofs + (long long)(row0 + rr) * ldc + lc;
                      if (OUT_BF16) ((bf16*)Cbase)[cidx] = (bf16)vv;
                      else          ((float*)Cbase)[cidx] = vv;
                  }
              }
          }
}

// ---------------------------------------------------------------------------
// concat(x, emb) -> bf16 [32768, 1088]; cols 1024..1055 emb, 1056..1087 zero
// ---------------------------------------------------------------------------
__global__ void concat_cast_kernel(const float* __restrict__ x,
                                   const float* __restrict__ emb,
                                   bf16* __restrict__ out)
{
    const int m = blockIdx.x;
    const int s = m & 511;
    const float* xr = x + (long long)m * 1024;
    bf16* orow = out + (long long)m * 1088;
    for (int g = threadIdx.x; g < 272; g += 256) {
        const int c = g * 4;
        float4 v;
        if (c < 1024)      v = *(const float4*)&xr[c];
        else if (c < 1056) v = *(const float4*)&emb[s * 32 + (c - 1024)];
        else               v = make_float4(0.f, 0.f, 0.f, 0.f);
        bf16 t[4] = { (bf16)v.x, (bf16)v.y, (bf16)v.z, (bf16)v.w };
        *(ushort4*)&orow[c] = *(ushort4*)t;
    }
}

// ---------------------------------------------------------------------------
// batched weight transpose-cast into bf16 [NP][1088] (zero-padded).
// ---------------------------------------------------------------------------
__global__ void wtrans5_kernel(const float* __restrict__ w1, const float* __restrict__ wq,
                               const float* __restrict__ wk, const float* __restrict__ wv,
                               const float* __restrict__ w2,
                               bf16* __restrict__ w1T, bf16* __restrict__ wqkvT,
                               bf16* __restrict__ w2T)
{
    const int z = blockIdx.z;
    const float* src; bf16* dst; int NIN, NP, srcld;
    switch (z) {
        case 0: src = w1; dst = w1T;                   NIN = 1056; NP = 1280; srcld = 1056; break;
        case 1: src = wq; dst = wqkvT;                 NIN = 1056; NP = 1152; srcld = 1056; break;
        case 2: src = wk; dst = wqkvT + 1152LL * 1088; NIN = 1056; NP = 1152; srcld = 1056; break;
        case 3: src = wv; dst = wqkvT + 2304LL * 1088; NIN = 1056; NP = 1280; srcld = 1056; break;
        default: src = w2; dst = w2T;                  NIN = 1024; NP = 1024; srcld = 1024; break;
    }
    const int KIN = 1056, KP = 1088;
    const int k0 = blockIdx.x * 32, n0 = blockIdx.y * 32;
    if (n0 >= NP) return;
    __shared__ float t[32][33];
    const int tx = threadIdx.x, ty = threadIdx.y;
    const int kk = k0 + ty, nn = n0 + tx;
    t[ty][tx] = (kk < KIN && nn < NIN) ? src[(long long)kk * srcld + nn] : 0.0f;
    __syncthreads();
    const int ko = k0 + tx, no = n0 + ty;
    if (no < NP && ko < KP)
        dst[(long long)no * KP + ko] = (bf16)t[tx][ty];
}

// ---------------------------------------------------------------------------
// bias prep: b1p[1280], bqkv[3456] (1152-seg), b2p[1024]
// ---------------------------------------------------------------------------
__global__ void biasprep_kernel(const float* __restrict__ b1, const float* __restrict__ bq,
                                const float* __restrict__ bk, const float* __restrict__ bv,
                                const float* __restrict__ b2,
                                float* __restrict__ b1p, float* __restrict__ bqkv,
                                float* __restrict__ b2p)
{
    const int i = blockIdx.x * 256 + threadIdx.x;
    if (i < 1280) {
        b1p[i] = (i < 1056) ? b1[i] : 0.0f;
    } else if (i < 1280 + 3456) {
        const int j = i - 1280;
        const int seg = j / 1152, c = j - seg * 1152;
        const float* src = seg == 0 ? bq : (seg == 1 ? bk : bv);
        bqkv[j] = (c < 1056) ? src[c] : 0.0f;
    } else if (i < 1280 + 3456 + 1024) {
        b2p[i - (1280 + 3456)] = b2[i - (1280 + 3456)];
    }
}

// ---------------------------------------------------------------------------
// batched bf16 transpose: v [64][512][1152] -> vT [64][1280][512]
// ---------------------------------------------------------------------------
__global__ void vtrans_kernel(const bf16* __restrict__ v, bf16* __restrict__ vt)
{
    __shared__ bf16 t[64][72];
    const long long b = blockIdx.z;
    const bf16* vb = v + b * (512LL * 1152);
    bf16* vtb = vt + b * (1280LL * 512);
    const int d0 = blockIdx.x * 64, s0 = blockIdx.y * 64;
    const int tx = threadIdx.x & 15, ty = threadIdx.x >> 4;   // 16x16
    const bool zz = d0 >= 1152;
    #pragma unroll
    for (int i = 0; i < 4; ++i) {
        const int row = ty + i * 16;
        ushort4 val = make_ushort4(0, 0, 0, 0);
        if (!zz)
            val = *(const ushort4*)&vb[(long long)(s0 + row) * 1152 + d0 + tx * 4];
        *(ushort4*)&t[row][tx * 4] = val;
    }
    __syncthreads();
    #pragma unroll
    for (int i = 0; i < 4; ++i) {
        const int d = ty + i * 16;
        ushort4 o;
        o.x = *(const ushort*)&t[tx * 4 + 0][d];
        o.y = *(const ushort*)&t[tx * 4 + 1][d];
        o.z = *(const ushort*)&t[tx * 4 + 2][d];
        o.w = *(const ushort*)&t[tx * 4 + 3][d];
        *(ushort4*)&vtb[(long long)(d0 + d) * 512 + s0 + tx * 4] = o;
    }
}

// ---------------------------------------------------------------------------
// row softmax: energy f32 [32768,512] -> attn bf16 [32768,512]; 1 wave/row
// ---------------------------------------------------------------------------
__global__ __launch_bounds__(256)
void softmax_kernel(const float* __restrict__ e, bf16* __restrict__ p)
{
    const int wid = threadIdx.x >> 6, lane = threadIdx.x & 63;
    const long long row = (long long)blockIdx.x * 4 + wid;
    const float* er = e + row * 512;
    float v[8];
    float mx = -3.0e38f;
    #pragma unroll
    for (int j = 0; j < 8; ++j) { v[j] = er[j * 64 + lane]; mx = fmaxf(mx, v[j]); }
    #pragma unroll
    for (int s = 32; s > 0; s >>= 1) mx = fmaxf(mx, __shfl_xor(mx, s));
    float sum = 0.0f;
    #pragma unroll
    for (int j = 0; j < 8; ++j) { v[j] = __expf(v[j] - mx); sum += v[j]; }
    #pragma unroll
    for (int s = 32; s > 0; s >>= 1) sum += __shfl_xor(sum, s);
    const float inv = 1.0f / sum;
    bf16* pr = p + row * 512;
    #pragma unroll
    for (int j = 0; j < 8; ++j) pr[j * 64 + lane] = (bf16)(v[j] * inv);
}

// ---------------------------------------------------------------------------
extern "C" void kernel_launch(void* const* d_in, const int* in_sizes, int n_in,
                              void* d_out, int out_size, void* d_ws, size_t ws_size,
                              hipStream_t stream)
{
    const float* x   = (const float*)d_in[0];
    const float* emb = (const float*)d_in[1];
    const float* w1  = (const float*)d_in[2];
    const float* b1  = (const float*)d_in[3];
    const float* wq  = (const float*)d_in[4];
    const float* bq  = (const float*)d_in[5];
    const float* wk  = (const float*)d_in[6];
    const float* bk  = (const float*)d_in[7];
    const float* wv  = (const float*)d_in[8];
    const float* bv  = (const float*)d_in[9];
    const float* w2  = (const float*)d_in[10];
    const float* b2  = (const float*)d_in[11];
    float* out = (float*)d_out;

    const long long Mrows = 32768;   // 64 * 512
    const int KR = 1088;             // compute K (17*64 >= 1056)
    const int WQ = 1152;             // stored width of q/k/v

    char* ws = (char*)d_ws;
    size_t off = 0;
    auto alloc = [&](size_t bytes) -> char* {
        char* p = ws + off;
        off += (bytes + 255) & ~(size_t)255;
        return p;
    };
    char* R1    = alloc((size_t)Mrows * KR * 2);            // hcat / energy / pv
    char* R2    = alloc((size_t)64 * 1280 * 512 * 2);       // h / vT
    bf16* qkv   = (bf16*)alloc((size_t)3 * Mrows * WQ * 2); // q | k | v
    bf16* w1T   = (bf16*)alloc((size_t)1280 * KR * 2);
    bf16* wqkvT = (bf16*)alloc((size_t)3584 * KR * 2);
    bf16* w2T   = (bf16*)alloc((size_t)1024 * KR * 2);
    float* b1p  = (float*)alloc((size_t)1280 * 4);
    float* bqkv = (float*)alloc((size_t)3456 * 4);
    float* b2p  = (float*)alloc((size_t)1024 * 4);

    bf16*  hcat   = (bf16*)R1;
    float* energy = (float*)R1;                 // after l1 consumed hcat
    bf16*  pv     = (bf16*)R1;                  // after softmax consumed energy
    bf16*  h      = (bf16*)R2;                  // [32768][1088]
    bf16*  vT     = (bf16*)R2;                  // after qkv consumed h
    bf16*  qb     = qkv;
    bf16*  kb     = qkv + Mrows * WQ;
    bf16*  vb     = qkv + 2 * Mrows * WQ;
    bf16*  attn   = kb;                         // k dead after energy

    concat_cast_kernel<<<32768, 256, 0, stream>>>(x, emb, hcat);
    wtrans5_kernel<<<dim3(34, 40, 5), dim3(32, 32), 0, stream>>>(
        w1, wq, wk, wv, w2, w1T, wqkvT, w2T);
    biasprep_kernel<<<23, 256, 0, stream>>>(b1, bq, bk, bv, b2, b1p, bqkv, b2p);

    // h = leaky_relu(hcat @ w1^T + b1)   M=32768 Ngrid=1280 K=1088
    gemm256<1, 1, 1, 0><<<dim3(5, 128, 1), 512, 0, stream>>>(
        hcat, w1T, h, b1p, KR, KR, KR, KR, KR, 0, 0, 0, 0);
    // q|k|v = h @ [wq|wk|wv]^T + bias    M=32768 Ngrid=3584 K=1088
    gemm256<1, 0, 1, 1><<<dim3(14, 128, 1), 512, 0, stream>>>(
        h, wqkvT, qkv, bqkv, KR, KR, KR, WQ, 3456, 0, 0, 0,
        (long long)Mrows * WQ);
    // vT (into dead h region)
    vtrans_kernel<<<dim3(20, 8, 64), 256, 0, stream>>>(vb, vT);
    // energy[b] = q_b @ k_b^T  (f32, into dead hcat region)
    gemm256<0, 0, 0, 0><<<dim3(2, 2, 64), 512, 0, stream>>>(
        qb, kb, energy, nullptr, KR, WQ, WQ, 512, 512,
        512LL * WQ, 512LL * WQ, 512LL * 512, 0);
    // softmax rows -> bf16 (into dead k region)
    softmax_kernel<<<8192, 256, 0, stream>>>(energy, attn);
    // pv[b] = attn_b @ v_b (via vT; into dead energy region)
    gemm256<1, 0, 0, 0><<<dim3(5, 2, 64), 512, 0, stream>>>(
        attn, vT, pv, nullptr, 512, 512, 512, KR, KR,
        512LL * 512, 1280LL * 512, 512LL * KR, 0);
    // out = pv @ w2 + b2  (f32)
    gemm256<0, 0, 1, 0><<<dim3(4, 128, 1), 512, 0, stream>>>(
        pv, w2T, out, b2p, KR, KR, KR, 1024, 1024, 0, 0, 0, 0);
}

// Round 9
// 633.463 us; speedup vs baseline: 1.1015x; 1.0564x over previous
//
#include <hip/hip_runtime.h>
#include <hip/hip_bf16.h>
#include <cstdint>

typedef __hip_bfloat16 bf16;
typedef __attribute__((ext_vector_type(8))) short short8;
typedef __attribute__((ext_vector_type(4))) float f32x4;

// ---------------------------------------------------------------------------
// async global->LDS, 16B/lane (wave-uniform LDS base + lane*16 implicit)
// ---------------------------------------------------------------------------
__device__ __forceinline__ void gload16(const bf16* g, bf16* l) {
    __builtin_amdgcn_global_load_lds(
        (__attribute__((address_space(1))) void*)g,
        (__attribute__((address_space(3))) void*)l, 16, 0, 0);
}
#define VMC(n) asm volatile("s_waitcnt vmcnt(" #n ")" ::: "memory")
__device__ __forceinline__ void bar() {
    asm volatile("" ::: "memory");
    __builtin_amdgcn_s_barrier();
    asm volatile("" ::: "memory");
}

// ---------------------------------------------------------------------------
// stage one half-tile [128 rows x 64 cols bf16] into a linear LDS region.
// Source pre-swizzled: LDS(r, slot) = G(r, slot ^ (r&7)) [16B slots].
// ---------------------------------------------------------------------------
__device__ __forceinline__ void stage_half(const bf16* __restrict__ G, int ld,
                                           int row0, int k0, bf16* lregion,
                                           int w, int lrow, int lslot)
{
    const bf16* s0 = G + (long long)(row0 + w * 8 + lrow) * ld + (k0 + lslot * 8);
    gload16(s0, lregion + (w * 64) * 8);
    gload16(s0 + (long long)64 * ld, lregion + (512 + w * 64) * 8);
}

// round-7 lesson: each wave reads ONLY its own region lds[b][0][wm]; any
// fragment read of tile t requires BOTH A stages of t drained.
#define LOAD_AI(dst, i_, mh, P) do { \
    _Pragma("unroll") for (int ks_ = 0; ks_ < 2; ++ks_) \
      dst[i_][ks_] = *(const short8*)((P) + ((mh) * 64 + (i_) * 16 + l15) * 64 \
                                         + (((ks_ * 4 + lq) ^ l7) * 8)); } while (0)
#define LOAD_B(nh, dst) do { _Pragma("unroll") for (int j_ = 0; j_ < 2; ++j_) { \
    _Pragma("unroll") for (int ks_ = 0; ks_ < 2; ++ks_) \
      dst[j_][ks_] = *(const short8*)(pb + (bhr + (nh) * 32 + j_ * 16 + l15) * 64 \
                                         + (((ks_ * 4 + lq) ^ l7) * 8)); } } while (0)
#define DO_Q(mh, nh, AF, BF) do { \
    __builtin_amdgcn_s_setprio(1); \
    _Pragma("unroll") for (int i_ = 0; i_ < 4; ++i_) \
      _Pragma("unroll") for (int j_ = 0; j_ < 2; ++j_) \
        _Pragma("unroll") for (int ks_ = 0; ks_ < 2; ++ks_) \
          acc[mh][nh][i_][j_] = __builtin_amdgcn_mfma_f32_16x16x32_bf16( \
              AF[i_][ks_], BF[j_][ks_], acc[mh][nh][i_][j_], 0, 0, 0); \
    __builtin_amdgcn_s_setprio(0); \
} while (0)

// ---------------------------------------------------------------------------
// 256x256 8-phase bf16 GEMM, C = A*B^T (+bias)(+leakyrelu).
// BIASMODE: 0 none; 1 bias[gc]; 3 bias[bz*512+gc] (energy c[t] term).
// ROUTE: 0 single output (ldc, batch sC);
//        2 dual output: gc<1152 -> Cbase (ld 1152) [v]; gc>=1152 ->
//          Cbase+segStride (ld 1088), local col gc-1152 [q'].
// Writes guarded by gc < nwrite.
// ---------------------------------------------------------------------------
template<int OUT_BF16, int ACT, int BIASMODE, int ROUTE>
__global__ __launch_bounds__(512, 2)
void gemm256(const bf16* __restrict__ Abase, const bf16* __restrict__ Bbase,
             void* __restrict__ Cbase, const float* __restrict__ bias,
             int K, int lda, int ldb, int ldc, int nwrite,
             long long sA, long long sB, long long sC, long long segStride)
{
    __shared__ bf16 lds[2][2][2][8192];   // [buf][op][half][128*64], 128 KiB

    // XCD-bijective chunk swizzle (T1/m204) over 3D linear block id
    const int gx = gridDim.x, gy = gridDim.y;
    const int nwg = gx * gy * gridDim.z;
    const int lin = blockIdx.x + gx * (blockIdx.y + gy * blockIdx.z);
    const int qch = nwg >> 3, rch = nwg & 7;
    const int xcd = lin & 7, pos = lin >> 3;
    const int nl = (xcd < rch ? xcd * (qch + 1)
                              : rch * (qch + 1) + (xcd - rch) * qch) + pos;
    const int bz = nl / (gx * gy);
    const int rem = nl - bz * (gx * gy);
    const int by = rem / gx;
    const int bx = rem - by * gx;

    const int tid = threadIdx.x;
    const int wid = tid >> 6, lane = tid & 63;
    const int wm = wid >> 2, wn = wid & 3;          // 2 x 4 waves
    const int l15 = lane & 15, l7 = lane & 7, lq = lane >> 4;
    const int lrow = lane >> 3, lslot = l7 ^ lrow;  // staging per-lane geom
    const int bhr = (wn & 1) * 64;                  // B row base within half

    const bf16* A = Abase + (long long)bz * sA;
    const bf16* B = Bbase + (long long)bz * sB;
    const int brow = by * 256, bcol = bx * 256;

    f32x4 acc[2][2][4][2] = {};
    short8 aFe[4][2], aFo[4][2], bF0[2][2], bF1[2][2];

    const int nt = K >> 6;

    // ---- prologue: t0.B, t0.A -> buf0 ; t1.B -> buf1 ----
    stage_half(B, ldb, bcol,       0,  &lds[0][1][0][0], wid, lrow, lslot);
    stage_half(B, ldb, bcol + 128, 0,  &lds[0][1][1][0], wid, lrow, lslot);
    stage_half(A, lda, brow,       0,  &lds[0][0][0][0], wid, lrow, lslot);
    stage_half(A, lda, brow + 128, 0,  &lds[0][0][1][0], wid, lrow, lslot);
    stage_half(B, ldb, bcol,       64, &lds[1][1][0][0], wid, lrow, lslot);
    stage_half(B, ldb, bcol + 128, 64, &lds[1][1][1][0], wid, lrow, lslot);
    VMC(4);   // drain B(0)+A(0); leaves B0(1),B1(1) = 4 (steady-state entry)
    bar();

    for (int t = 0; t < nt; ++t) {
        const int b = t & 1;
        const bf16* pa = &lds[b][0][wm][0];
        const bf16* pb = &lds[b][1][wn >> 1][0];
        bf16* oA = &lds[b ^ 1][0][0][0];   // next tile's A -> other buffer
        bf16* cB = &lds[b][1][0][0];       // tile t+2's B -> current buffer
        const int t1 = (t + 1 == nt) ? 0 : t + 1;
        const int t2 = (t + 2 >= nt) ? t + 2 - nt : t + 2;
        const int k1 = t1 << 6, k2 = t2 << 6;

        // ---- p1: read aFe + both B halves; stage A0(t+1); Q(0,0) ----
        LOAD_B(0, bF0);
        LOAD_AI(aFe, 0, 0, pa); LOAD_AI(aFe, 1, 0, pa);
        LOAD_AI(aFe, 2, 0, pa); LOAD_AI(aFe, 3, 0, pa);
        LOAD_B(1, bF1);
        stage_half(A, lda, brow, k1, oA, wid, lrow, lslot);
        bar();
        DO_Q(0, 0, aFe, bF0);
        bar();

        // ---- p2: read aFo[0,1]; stage A1(t+1); Q(0,1) ----
        LOAD_AI(aFo, 0, 1, pa); LOAD_AI(aFo, 1, 1, pa);
        stage_half(A, lda, brow + 128, k1, oA + 8192, wid, lrow, lslot);
        bar();
        DO_Q(0, 1, aFe, bF1);
        bar();

        // ---- p3: read aFo[2,3]; stage B0(t+2); Q(1,1) ----
        LOAD_AI(aFo, 2, 1, pa); LOAD_AI(aFo, 3, 1, pa);
        stage_half(B, ldb, bcol, k2, cB, wid, lrow, lslot);
        bar();
        DO_Q(1, 1, aFo, bF1);
        bar();

        // ---- p4: stage B1(t+2); Q(1,0); tile-boundary drain ----
        stage_half(B, ldb, bcol + 128, k2, cB + 8192, wid, lrow, lslot);
        bar();
        DO_Q(1, 0, aFo, bF0);
        VMC(4);   // drain B(t+1)+A(t+1); B(t+2) pair stays in flight
        bar();
    }
    VMC(0);   // drain wrapped stray stages

    // ---- epilogue: C/D layout col = lane&15, row = (lane>>4)*4 + rr ----
    const long long cofs0 = (long long)bz * sC;
    #pragma unroll
    for (int mh = 0; mh < 2; ++mh)
      #pragma unroll
      for (int nh = 0; nh < 2; ++nh)
        #pragma unroll
        for (int i = 0; i < 4; ++i)
          #pragma unroll
          for (int j = 0; j < 2; ++j) {
              const int gc = bcol + wn * 64 + nh * 32 + j * 16 + l15;
              const bool wr = gc < nwrite;
              const int row0 = brow + wm * 128 + mh * 64 + i * 16 + lq * 4;
              if (wr) {
                  float bvv = 0.0f;
                  if (BIASMODE == 1) bvv = bias[gc];
                  if (BIASMODE == 3) bvv = bias[(long long)bz * 512 + gc];
                  long long base; int lc, ld;
                  if (ROUTE == 2) {
                      if (gc < 1152) { base = 0; lc = gc; ld = 1152; }
                      else { base = segStride; lc = gc - 1152; ld = 1088; }
                  } else { base = cofs0; lc = gc; ld = ldc; }
                  #pragma unroll
                  for (int rr = 0; rr < 4; ++rr) {
                      float vv = acc[mh][nh][i][j][rr] + bvv;
                      if (ACT) vv = vv > 0.0f ? vv : 0.2f * vv;
                      const long long cidx = base + (long long)(row0 + rr) * ld + lc;
                      if (OUT_BF16) ((bf16*)Cbase)[cidx] = (bf16)vv;
                      else          ((float*)Cbase)[cidx] = vv;
                  }
              }
          }
}

// ---------------------------------------------------------------------------
// concat(x, emb) -> bf16 [32768, 1088]; cols 1024..1055 emb, 1056..1087 zero
// ---------------------------------------------------------------------------
__global__ void concat_cast_kernel(const float* __restrict__ x,
                                   const float* __restrict__ emb,
                                   bf16* __restrict__ out)
{
    const int m = blockIdx.x;
    const int s = m & 511;
    const float* xr = x + (long long)m * 1024;
    bf16* orow = out + (long long)m * 1088;
    for (int g = threadIdx.x; g < 272; g += 256) {
        const int c = g * 4;
        float4 v;
        if (c < 1024)      v = *(const float4*)&xr[c];
        else if (c < 1056) v = *(const float4*)&emb[s * 32 + (c - 1024)];
        else               v = make_float4(0.f, 0.f, 0.f, 0.f);
        bf16 t[4] = { (bf16)v.x, (bf16)v.y, (bf16)v.z, (bf16)v.w };
        *(ushort4*)&orow[c] = *(ushort4*)t;
    }
}

// ---------------------------------------------------------------------------
// weight transpose-cast: z=0 w1->w1T[1280][1088]; z=1 wv->Bqv rows 0..1151;
// z=2 w2->w2T[1024][1088]. Zero-padded outside source extents.
// ---------------------------------------------------------------------------
__global__ void wtrans3_kernel(const float* __restrict__ w1, const float* __restrict__ wv,
                               const float* __restrict__ w2,
                               bf16* __restrict__ w1T, bf16* __restrict__ Bqv,
                               bf16* __restrict__ w2T)
{
    const int z = blockIdx.z;
    const float* src; bf16* dst; int NIN, NP, srcld;
    switch (z) {
        case 0: src = w1; dst = w1T; NIN = 1056; NP = 1280; srcld = 1056; break;
        case 1: src = wv; dst = Bqv; NIN = 1056; NP = 1152; srcld = 1056; break;
        default: src = w2; dst = w2T; NIN = 1024; NP = 1024; srcld = 1024; break;
    }
    const int KIN = 1056, KP = 1088;
    const int k0 = blockIdx.x * 32, n0 = blockIdx.y * 32;
    if (n0 >= NP) return;
    __shared__ float t[32][33];
    const int tx = threadIdx.x, ty = threadIdx.y;
    const int kk = k0 + ty, nn = n0 + tx;
    t[ty][tx] = (kk < KIN && nn < NIN) ? src[(long long)kk * srcld + nn] : 0.0f;
    __syncthreads();
    const int ko = k0 + tx, no = n0 + ty;
    if (no < NP && ko < KP)
        dst[(long long)no * KP + ko] = (bf16)t[tx][ty];
}

// ---------------------------------------------------------------------------
// cast-only (no transpose): wq,wk f32 [1056][1056] -> bf16 [1280][1088] pad
// ---------------------------------------------------------------------------
__global__ void wcast2_kernel(const float* __restrict__ wq, const float* __restrict__ wk,
                              bf16* __restrict__ wqC, bf16* __restrict__ wkC)
{
    const int i = blockIdx.x;
    const float* src = blockIdx.y ? wk : wq;
    bf16* dst = blockIdx.y ? wkC : wqC;
    for (int c = threadIdx.x; c < 1088; c += 256) {
        float v = (i < 1056 && c < 1056) ? src[(long long)i * 1056 + c] : 0.0f;
        dst[(long long)i * 1088 + c] = (bf16)v;
    }
}

// ---------------------------------------------------------------------------
// u[e] = sum_o wk[e][o] * bq[o]  (e<1056; pad 0) -- one wave per e
// ---------------------------------------------------------------------------
__global__ void uvec_kernel(const float* __restrict__ wk, const float* __restrict__ bq,
                            float* __restrict__ u)
{
    const int wid = threadIdx.x >> 6, lane = threadIdx.x & 63;
    const int e = blockIdx.x * 4 + wid;
    if (e >= 1088) return;
    float s = 0.0f;
    if (e < 1056) {
        for (int d = lane; d < 1056; d += 64)
            s += wk[(long long)e * 1056 + d] * bq[d];
    }
    #pragma unroll
    for (int sh = 32; sh > 0; sh >>= 1) s += __shfl_xor(s, sh);
    if (lane == 0) u[e] = s;
}

// ---------------------------------------------------------------------------
// c[m] = dot(h[m][0..1087], u)  -- one wave per row (c = bq . k-term)
// ---------------------------------------------------------------------------
__global__ __launch_bounds__(256)
void cvec_kernel(const bf16* __restrict__ h, const float* __restrict__ u,
                 float* __restrict__ c)
{
    const int wid = threadIdx.x >> 6, lane = threadIdx.x & 63;
    const long long row = (long long)blockIdx.x * 4 + wid;
    const bf16* hr = h + row * 1088;
    float s = 0.0f;
    #pragma unroll
    for (int j = 0; j < 17; ++j)
        s += (float)hr[j * 64 + lane] * u[j * 64 + lane];
    #pragma unroll
    for (int sh = 32; sh > 0; sh >>= 1) s += __shfl_xor(s, sh);
    if (lane == 0) c[row] = s;
}

// ---------------------------------------------------------------------------
// bias prep: b1p[1088], bqv2[2304] ([0..1151]=bv pad, rest 0), b2p[1024]
// ---------------------------------------------------------------------------
__global__ void biasprep_kernel(const float* __restrict__ b1, const float* __restrict__ bv,
                                const float* __restrict__ b2,
                                float* __restrict__ b1p, float* __restrict__ bqv2,
                                float* __restrict__ b2p)
{
    const int i = blockIdx.x * 256 + threadIdx.x;
    if (i < 1088) {
        b1p[i] = (i < 1056) ? b1[i] : 0.0f;
    } else if (i < 1088 + 2304) {
        const int j = i - 1088;
        bqv2[j] = (j < 1056) ? bv[j] : 0.0f;
    } else if (i < 1088 + 2304 + 1024) {
        b2p[i - (1088 + 2304)] = b2[i - (1088 + 2304)];
    }
}

// ---------------------------------------------------------------------------
// batched bf16 transpose: v [64][512][1152] -> vT [64][1280][512]
// ---------------------------------------------------------------------------
__global__ void vtrans_kernel(const bf16* __restrict__ v, bf16* __restrict__ vt)
{
    __shared__ bf16 t[64][72];
    const long long b = blockIdx.z;
    const bf16* vb = v + b * (512LL * 1152);
    bf16* vtb = vt + b * (1280LL * 512);
    const int d0 = blockIdx.x * 64, s0 = blockIdx.y * 64;
    const int tx = threadIdx.x & 15, ty = threadIdx.x >> 4;   // 16x16
    const bool zz = d0 >= 1152;
    #pragma unroll
    for (int i = 0; i < 4; ++i) {
        const int row = ty + i * 16;
        ushort4 val = make_ushort4(0, 0, 0, 0);
        if (!zz)
            val = *(const ushort4*)&vb[(long long)(s0 + row) * 1152 + d0 + tx * 4];
        *(ushort4*)&t[row][tx * 4] = val;
    }
    __syncthreads();
    #pragma unroll
    for (int i = 0; i < 4; ++i) {
        const int d = ty + i * 16;
        ushort4 o;
        o.x = *(const ushort*)&t[tx * 4 + 0][d];
        o.y = *(const ushort*)&t[tx * 4 + 1][d];
        o.z = *(const ushort*)&t[tx * 4 + 2][d];
        o.w = *(const ushort*)&t[tx * 4 + 3][d];
        *(ushort4*)&vtb[(long long)(d0 + d) * 512 + s0 + tx * 4] = o;
    }
}

// ---------------------------------------------------------------------------
// row softmax: energy f32 [32768,512] -> attn bf16 [32768,512]; 1 wave/row
// ---------------------------------------------------------------------------
__global__ __launch_bounds__(256)
void softmax_kernel(const float* __restrict__ e, bf16* __restrict__ p)
{
    const int wid = threadIdx.x >> 6, lane = threadIdx.x & 63;
    const long long row = (long long)blockIdx.x * 4 + wid;
    const float* er = e + row * 512;
    float v[8];
    float mx = -3.0e38f;
    #pragma unroll
    for (int j = 0; j < 8; ++j) { v[j] = er[j * 64 + lane]; mx = fmaxf(mx, v[j]); }
    #pragma unroll
    for (int s = 32; s > 0; s >>= 1) mx = fmaxf(mx, __shfl_xor(mx, s));
    float sum = 0.0f;
    #pragma unroll
    for (int j = 0; j < 8; ++j) { v[j] = __expf(v[j] - mx); sum += v[j]; }
    #pragma unroll
    for (int s = 32; s > 0; s >>= 1) sum += __shfl_xor(sum, s);
    const float inv = 1.0f / sum;
    bf16* pr = p + row * 512;
    #pragma unroll
    for (int j = 0; j < 8; ++j) pr[j * 64 + lane] = (bf16)(v[j] * inv);
}

// ---------------------------------------------------------------------------
extern "C" void kernel_launch(void* const* d_in, const int* in_sizes, int n_in,
                              void* d_out, int out_size, void* d_ws, size_t ws_size,
                              hipStream_t stream)
{
    const float* x   = (const float*)d_in[0];
    const float* emb = (const float*)d_in[1];
    const float* w1  = (const float*)d_in[2];
    const float* b1  = (const float*)d_in[3];
    const float* wq  = (const float*)d_in[4];
    const float* bq  = (const float*)d_in[5];
    const float* wk  = (const float*)d_in[6];
    // const float* bk = (const float*)d_in[7];  // drops under softmax shift
    const float* wv  = (const float*)d_in[8];
    const float* bv  = (const float*)d_in[9];
    const float* w2  = (const float*)d_in[10];
    const float* b2  = (const float*)d_in[11];
    float* out = (float*)d_out;

    const long long Mrows = 32768;   // 64 * 512
    const int KR = 1088;             // compute K (17*64 >= 1056)

    char* ws = (char*)d_ws;
    size_t off = 0;
    auto alloc = [&](size_t bytes) -> char* {
        char* p = ws + off;
        off += (bytes + 255) & ~(size_t)255;
        return p;
    };
    char* R1   = alloc((size_t)Mrows * KR * 2);          // hcat -> energy -> pv
    char* Rh   = alloc((size_t)Mrows * KR * 2);          // h (lives to energy)
    char* Rq   = alloc((size_t)Mrows * KR * 2);          // q' -> attn
    bf16* vbuf = (bf16*)alloc((size_t)Mrows * 1152 * 2); // v
    bf16* vT   = (bf16*)alloc((size_t)64 * 1280 * 512 * 2);
    bf16* w1T  = (bf16*)alloc((size_t)1280 * KR * 2);
    bf16* Bqv  = (bf16*)alloc((size_t)2432 * KR * 2);    // [0..1151]=wvT, [1152..2431]=M^T
    bf16* w2T  = (bf16*)alloc((size_t)1024 * KR * 2);
    bf16* wqC  = (bf16*)alloc((size_t)1280 * KR * 2);
    bf16* wkC  = (bf16*)alloc((size_t)1280 * KR * 2);
    float* b1p  = (float*)alloc((size_t)1088 * 4);
    float* bqv2 = (float*)alloc((size_t)2304 * 4);
    float* b2p  = (float*)alloc((size_t)1024 * 4);
    float* uvec = (float*)alloc((size_t)1088 * 4);
    float* cvec = (float*)alloc((size_t)Mrows * 4);

    bf16*  hcat   = (bf16*)R1;
    float* energy = (float*)R1;       // after l1 consumed hcat (67MB <= 71MB)
    bf16*  pv     = (bf16*)R1;        // after softmax consumed energy
    bf16*  h      = (bf16*)Rh;        // [32768][1088], alive until energy
    bf16*  qbuf   = (bf16*)Rq;        // q' [32768][1088]
    bf16*  attn   = (bf16*)Rq;        // after energy consumed q'

    concat_cast_kernel<<<32768, 256, 0, stream>>>(x, emb, hcat);
    wtrans3_kernel<<<dim3(34, 40, 3), dim3(32, 32), 0, stream>>>(
        w1, wv, w2, w1T, Bqv, w2T);
    wcast2_kernel<<<dim3(1280, 2), 256, 0, stream>>>(wq, wk, wqC, wkC);
    uvec_kernel<<<272, 256, 0, stream>>>(wk, bq, uvec);
    biasprep_kernel<<<18, 256, 0, stream>>>(b1, bv, b2, b1p, bqv2, b2p);

    // M^T = Wk @ Wq^T  -> Bqv rows 1152..2431 (rows >=2240 are zero via A-pad)
    gemm256<1, 0, 0, 0><<<dim3(5, 5, 1), 512, 0, stream>>>(
        wkC, wqC, Bqv + 1152LL * KR, nullptr, KR, KR, KR, KR, KR, 0, 0, 0, 0);
    // h = leaky_relu(hcat @ w1^T + b1)   M=32768 Ngrid=1280 K=1088
    gemm256<1, 1, 1, 0><<<dim3(5, 128, 1), 512, 0, stream>>>(
        hcat, w1T, h, b1p, KR, KR, KR, KR, KR, 0, 0, 0, 0);
    // c[m] = h[m] . u   (bq-dependent energy column term; 0 when bq==0)
    cvec_kernel<<<8192, 256, 0, stream>>>(h, uvec, cvec);
    // v | q' = h @ Bqv^T (+bv for v)     M=32768 Ngrid=2304 K=1088, dual-out
    gemm256<1, 0, 1, 2><<<dim3(9, 128, 1), 512, 0, stream>>>(
        h, Bqv, vbuf, bqv2, KR, KR, KR, 0, 2240, 0, 0, 0,
        (long long)(qbuf - vbuf));
    // vT (standalone buffer)
    vtrans_kernel<<<dim3(20, 8, 64), 256, 0, stream>>>(vbuf, vT);
    // energy[b] = q'_b @ h_b^T + c[t]  (f32, into dead hcat region)
    gemm256<0, 0, 3, 0><<<dim3(2, 2, 64), 512, 0, stream>>>(
        qbuf, h, energy, cvec, KR, KR, KR, 512, 512,
        512LL * KR, 512LL * KR, 512LL * 512, 0);
    // softmax rows -> bf16 (into dead q' region)
    softmax_kernel<<<8192, 256, 0, stream>>>(energy, attn);
    // pv[b] = attn_b @ v_b (via vT; into dead energy region)
    gemm256<1, 0, 0, 0><<<dim3(5, 2, 64), 512, 0, stream>>>(
        attn, vT, pv, nullptr, 512, 512, 512, KR, KR,
        512LL * 512, 1280LL * 512, 512LL * KR, 0);
    // out = pv @ w2 + b2  (f32)
    gemm256<0, 0, 1, 0><<<dim3(4, 128, 1), 512, 0, stream>>>(
        pv, w2T, out, b2p, KR, KR, KR, 1024, 1024, 0, 0, 0, 0);
}